// Round 13
// baseline (194.454 us; speedup 1.0000x reference)
//
#include <hip/hip_runtime.h>
#include <cstdint>

using u32 = unsigned int;
using u64 = unsigned long long;

#define WDIM 512
#define HDIM 512
#define CHANNELS 80   // 8 batches * 10 classes
#define NSTRIP 8      // row-strips per channel (64 rows each)
#define STRIPROWS 64
#define KEYCAP 4096   // per-strip survivor cap (expected ~3.7k, sd ~60)
#define HBINS 4096
#define FINCAP 256    // per-strip finalist cap (expected ~130, sd ~12)
#define MERGEN 2048   // merge sort size = NSTRIP * FINCAP
#define TOPK 100
#define NEG_SENTINEL -1e30f

__device__ __forceinline__ float fmax3(float a, float b, float c) {
  return fmaxf(fmaxf(a, b), c);
}

// bin from float bits: 512 bins/octave, offset so v>=2^-8 maps above 0.
// Monotonic in v; clamp below. Max (v<1.0): (1065353215>>14)-60928 = 4095.
__device__ __forceinline__ int key_bin(u64 key) {
  int b = (int)((u32)(key >> 32) >> 14) - 60928;
  return b < 0 ? 0 : b;
}

struct H8 { float h0, h1, h2, h3, h4, h5, h6, h7; };
struct Row { float l; float4 A; float4 B; float r; };

// Load 8 px of row y at x0 = lane*8 (two float4); horizontal neighbors via
// wave shuffles (one wave = one full 512-px row).
__device__ __forceinline__ Row load_row_shfl(const float* __restrict__ chbase,
                                             int y, int x0) {
  Row o;
  if (y >= 0 && y < HDIM) {
    const float* row = chbase + (size_t)y * WDIM;
    o.A = *reinterpret_cast<const float4*>(row + x0);
    o.B = *reinterpret_cast<const float4*>(row + x0 + 4);
  } else {
    o.A = make_float4(NEG_SENTINEL, NEG_SENTINEL, NEG_SENTINEL, NEG_SENTINEL);
    o.B = o.A;
  }
  o.l = __shfl_up(o.B.w, 1);
  o.r = __shfl_down(o.A.x, 1);
  int lane = threadIdx.x & 63;
  if (lane == 0) o.l = NEG_SENTINEL;    // x == 0 edge
  if (lane == 63) o.r = NEG_SENTINEL;   // x == 511 edge
  return o;
}

__device__ __forceinline__ H8 hmax_row(const Row& t) {
  H8 o;
  o.h0 = fmax3(t.l,   t.A.x, t.A.y);
  o.h1 = fmax3(t.A.x, t.A.y, t.A.z);
  o.h2 = fmax3(t.A.y, t.A.z, t.A.w);
  o.h3 = fmax3(t.A.z, t.A.w, t.B.x);
  o.h4 = fmax3(t.A.w, t.B.x, t.B.y);
  o.h5 = fmax3(t.B.x, t.B.y, t.B.z);
  o.h6 = fmax3(t.B.y, t.B.z, t.B.w);
  o.h7 = fmax3(t.B.z, t.B.w, t.r);
  return o;
}

// key = (float_bits(v) << 32) | ~index : desc sort == (value desc, index asc)
__device__ __forceinline__ void bitonic_desc(u64* keys, int N, int nthr, int tid) {
  for (unsigned size = 2; size <= (unsigned)N; size <<= 1) {
    for (unsigned stride = size >> 1; stride > 0; stride >>= 1) {
      __syncthreads();
      for (unsigned i = tid; i < (unsigned)N; i += nthr) {
        unsigned j = i ^ stride;
        if (j > i) {
          u64 a = keys[i], b = keys[j];
          bool desc = ((i & size) == 0);
          if ((a < b) == desc) { keys[i] = b; keys[j] = a; }
        }
      }
    }
  }
  __syncthreads();
}

// ---- fused: 3x3 NMS + per-strip finalist selection (no sort in strip) ----
// grid = (NSTRIP, CHANNELS), 512 threads (8 waves; wave w rolls rows w*8..w*8+7).
// Emits ALL survivors in bins >= per-strip threshold T (suffix >= 100), i.e. a
// superset of the strip top-100, unsorted; merge_channel sorts exactly.
__global__ __launch_bounds__(512) void nms_topk_strip(
    const float* __restrict__ heat, u64* __restrict__ fin, u32* __restrict__ fcnt) {
  const int strip = blockIdx.x, ch = blockIdx.y;
  const float* chbase = heat + (size_t)ch * (WDIM * HDIM);

  __shared__ u64 keys[KEYCAP];
  __shared__ u32 hist[HBINS];
  __shared__ u32 lcnt, scand;
  __shared__ int sT;

  for (int i = threadIdx.x; i < HBINS; i += 512) hist[i] = 0;
  if (threadIdx.x == 0) { lcnt = 0; scand = 0; }
  __syncthreads();

  const int lane = threadIdx.x & 63;
  const u64 lmlt = (1ULL << lane) - 1;  // lanes-below mask
  const int wave = threadIdx.x >> 6;
  const int x0 = lane * 8;
  const int yb = strip * STRIPROWS + wave * 8;

  Row rm = load_row_shfl(chbase, yb, x0);
  H8 ht = hmax_row(load_row_shfl(chbase, yb - 1, x0));
  H8 hm = hmax_row(rm);

  for (int j = 0; j < 8; j++) {
    const int y = yb + j;
    Row rb = load_row_shfl(chbase, y + 1, x0);
    H8 hb = hmax_row(rb);
    const int P = (y << 9) + x0;

    // ballot-compacted append: one LDS atomic per wave-ballot, not per survivor
#define DO_PIX(I, VC, HX)                                                   \
    {                                                                       \
      float v = (VC);                                                       \
      bool pred = (v == fmax3(ht.HX, hm.HX, hb.HX)) && (v > 0.0f);          \
      u64 m = __ballot(pred);                                               \
      if (m) {                                                              \
        u32 cnt = (u32)__popcll(m);                                         \
        u32 wbase = 0;                                                      \
        if (lane == 0) wbase = atomicAdd(&lcnt, cnt);                       \
        wbase = __shfl(wbase, 0);                                           \
        if (pred) {                                                         \
          u32 pos = wbase + (u32)__popcll(m & lmlt);                        \
          if (pos < KEYCAP)                                                 \
            keys[pos] = ((u64)__float_as_uint(v) << 32) |                   \
                        (u32)(~(u32)(P + (I)));                             \
        }                                                                   \
      }                                                                     \
    }
    DO_PIX(0, rm.A.x, h0)
    DO_PIX(1, rm.A.y, h1)
    DO_PIX(2, rm.A.z, h2)
    DO_PIX(3, rm.A.w, h3)
    DO_PIX(4, rm.B.x, h4)
    DO_PIX(5, rm.B.y, h5)
    DO_PIX(6, rm.B.z, h6)
    DO_PIX(7, rm.B.w, h7)
#undef DO_PIX

    rm = rb; ht = hm; hm = hb;
  }

  __syncthreads();
  const int n = min((int)lcnt, KEYCAP);

  // histogram of strip survivors (scattered bins -> low contention)
  for (int i = threadIdx.x; i < n; i += 512)
    atomicAdd(&hist[key_bin(keys[i])], 1u);
  __syncthreads();

  // smallest bin T with suffix count >= TOPK (~14 iters: top octave dense)
  if (threadIdx.x == 0) {
    u32 cum = 0;
    int b = HBINS - 1;
    for (; b >= 0; b--) {
      cum += hist[b];
      if (cum >= TOPK) break;
    }
    sT = b < 0 ? 0 : b;
  }
  __syncthreads();
  const int T = sT;

  // compact finalists (bin >= T) straight to global, ballot-batched
  u64* dst = fin + ((size_t)ch * NSTRIP + strip) * FINCAP;
  for (int i = threadIdx.x; i < ((n + 511) & ~511); i += 512) {
    u64 k = (i < n) ? keys[i] : 0;
    bool pred = (i < n) && (key_bin(k) >= T);
    u64 m = __ballot(pred);
    if (m) {
      u32 cnt = (u32)__popcll(m);
      u32 wbase = 0;
      if (lane == 0) wbase = atomicAdd(&scand, cnt);
      wbase = __shfl(wbase, 0);
      if (pred) {
        u32 pos = wbase + (u32)__popcll(m & lmlt);
        if (pos < FINCAP) dst[pos] = k;
      }
    }
  }
  __syncthreads();
  if (threadIdx.x == 0)
    fcnt[ch * NSTRIP + strip] = min(scand, (u32)FINCAP);
}

// ---- per-channel merge: <=8*256 finalist keys -> exact channel top-100 ----
__global__ __launch_bounds__(512) void merge_channel(
    const u64* __restrict__ fin, const u32* __restrict__ fcnt,
    u64* __restrict__ chtop) {
  const int ch = blockIdx.x;
  __shared__ u64 sk[MERGEN];
  __shared__ u32 cnts[NSTRIP];
  if (threadIdx.x < NSTRIP) cnts[threadIdx.x] = fcnt[ch * NSTRIP + threadIdx.x];
  __syncthreads();
  const u64* src = fin + (size_t)ch * NSTRIP * FINCAP;
  for (int i = threadIdx.x; i < MERGEN; i += 512) {
    int s = i >> 8, j = i & (FINCAP - 1);
    sk[i] = (j < (int)cnts[s]) ? src[s * FINCAP + j] : 0;
  }
  bitonic_desc(sk, MERGEN, 512, threadIdx.x);
  for (int k = threadIdx.x; k < TOPK; k += 512)
    chtop[(size_t)ch * TOPK + k] = sk[k];
}

// ---- per-batch top-100 over the 10*100 channel candidates ----
__global__ __launch_bounds__(256) void batch_topk_kernel(
    const u64* __restrict__ chtop, float* __restrict__ out) {
  const int b = blockIdx.x;
  __shared__ u64 sk[1024];
  const u64* base = chtop + (size_t)b * 10 * TOPK;
  for (int i = threadIdx.x; i < 1024; i += 256) {
    u64 k = 0;
    if (i < 1000) {
      u32 vb = (u32)(base[i] >> 32);
      k = ((u64)vb << 32) | (u32)(~(u32)i);  // tie-break: lower flat idx first
    }
    sk[i] = k;
  }
  bitonic_desc(sk, 1024, 256, threadIdx.x);
  for (int k = threadIdx.x; k < TOPK; k += 256) {
    u64 key = sk[k];
    float sc = __uint_as_float((u32)(key >> 32));
    int flat = (int)(~(u32)key);                     // c*100 + j
    int cls = flat / 100;
    int spatial = (int)(~(u32)(base[flat]));         // low 32 = ~spatial
    out[0 * 800 + b * TOPK + k] = sc;
    out[1 * 800 + b * TOPK + k] = (float)spatial;
    out[2 * 800 + b * TOPK + k] = (float)cls;
    out[3 * 800 + b * TOPK + k] = (float)(spatial >> 9);   // y
    out[4 * 800 + b * TOPK + k] = (float)(spatial & 511);  // x
  }
}

extern "C" void kernel_launch(void* const* d_in, const int* in_sizes, int n_in,
                              void* d_out, int out_size, void* d_ws, size_t ws_size,
                              hipStream_t stream) {
  const float* heat = (const float*)d_in[0];
  char* ws = (char*)d_ws;
  float* out = (float*)d_out;

  size_t p = 0;
  u64* fin   = (u64*)(ws + p); p += (size_t)CHANNELS * NSTRIP * FINCAP * 8;  // 1.25 MB
  u32* fcnt  = (u32*)(ws + p); p += (size_t)CHANNELS * NSTRIP * 4;
  p = (p + 255) & ~(size_t)255;
  u64* chtop = (u64*)(ws + p); p += (size_t)CHANNELS * TOPK * 8;             // 64 KB

  dim3 gridA(NSTRIP, CHANNELS);  // 640 blocks, 8 waves each
  nms_topk_strip<<<gridA, 512, 0, stream>>>(heat, fin, fcnt);
  merge_channel<<<CHANNELS, 512, 0, stream>>>(fin, fcnt, chtop);
  batch_topk_kernel<<<8, 256, 0, stream>>>(chtop, out);
}